// Round 4
// baseline (78.923 us; speedup 1.0000x reference)
//
#include <hip/hip_runtime.h>
#include <hip/hip_bf16.h>

// Quantizer (VQ-VAE): inputs [32,2048,256] f32, embed [1024,256] f32.
// out = (quantized [32,2048,256] f32, latent_loss scalar f32) concatenated.
//
// Pipeline:
//   prep_kernel : embed -> bf16 PRE-SWIZZLED copy (ws) + cneg[k] = -0.5*||e_k||^2
//   vq_kernel   : X->regs (staged in 2 halves), Es DOUBLE-BUFFERED chunks via
//                 global_load_lds prefetch-ahead, bf16-MFMA argmin,
//                 fused q = ew[code] nontemporal write + algebraic loss partials
//   loss_kernel : final reduce -> 1.25 * [sum(x^2) - 2*sum(sv_win)] / (N*D)
//
// loss algebra: ||x-e||^2 = ||x||^2 - 2*(x.e - 0.5||e||^2) = ||x||^2 - 2*sv.

#define DIM     256
#define M_ROWS  65536
#define NCODES  1024
#define CHUNK   64            // codes per Es chunk (32 KiB)
#define NCHUNK  16

using bf16x8  = __attribute__((ext_vector_type(8))) short;
using f32x4   = __attribute__((ext_vector_type(4))) float;   // ext-vector: ok for nontemporal builtins
using short4v = __attribute__((ext_vector_type(4))) short;

__device__ inline short f2bf(float f) {
  union { __hip_bfloat16 h; short s; } u;
  u.h = __float2bfloat16(f);   // RTNE
  return u.s;
}

__device__ inline void gload_lds16(const short* g, short* l) {
  __builtin_amdgcn_global_load_lds(
      (const __attribute__((address_space(1))) void*)g,
      (__attribute__((address_space(3))) void*)l, 16, 0, 0);
}

// ---------------------------------------------------------------- prep
// ebf layout: row-major [code][256] bf16; 16B units within each row permuted
// u -> u ^ (code & 15). vq stages rows linearly into LDS (global_load_lds),
// reads with the same XOR -> conflict-free ds_read_b128.
__global__ __launch_bounds__(64) void prep_kernel(const float* __restrict__ ew,
                                                  short* __restrict__ ebf,
                                                  float* __restrict__ cneg) {
  const int code = blockIdx.x;
  const int t    = threadIdx.x;
  f32x4 v = *((const f32x4*)(ew + (size_t)code * DIM) + t);
  short4v o;
  o.x = f2bf(v[0]); o.y = f2bf(v[1]); o.z = f2bf(v[2]); o.w = f2bf(v[3]);
  int u = t >> 1, h = t & 1;
  int off = code * 256 + ((u ^ (code & 15)) << 3) + h * 4;
  *(short4v*)(ebf + off) = o;
  float ss = v[0] * v[0] + v[1] * v[1] + v[2] * v[2] + v[3] * v[3];
#pragma unroll
  for (int off2 = 32; off2 > 0; off2 >>= 1) ss += __shfl_xor(ss, off2, 64);
  if (t == 0) cneg[code] = -0.5f * ss;
}

// ---------------------------------------------------------------- fused vq
__global__ __launch_bounds__(256, 2) void vq_kernel(const float* __restrict__ x,
                                                    const short* __restrict__ ebf,
                                                    const float* __restrict__ cneg,
                                                    const float* __restrict__ ew,
                                                    float* __restrict__ qout,
                                                    float* __restrict__ partials) {
  __shared__ short buf[2][CHUNK * 256];   // 2 x 32 KiB: Es dbuf; buf[1] also X-staging
  __shared__ float cands[2][128];
  __shared__ int   codes[128];
  __shared__ float red[256];

  const int tid  = threadIdx.x;
  const int lane = tid & 63;
  const int wid  = tid >> 6;
  const int wr   = wid >> 1;           // wave row group (0..1), 64 rows each
  const int wc   = wid & 1;            // wave col group (0..1), 32 codes/chunk each
  const int l15  = lane & 15;
  const int lhi  = lane >> 4;          // 0..3
  const int row0 = blockIdx.x * 128;

  // ---- prefetch Es chunk 0 into buf[0] (overlaps the X read burst) ----
#pragma unroll
  for (int it = 0; it < 8; ++it)
    gload_lds16(ebf + it * 2048 + tid * 8, &buf[0][it * 2048 + tid * 8]);

  // ---- stage X in two 64-row halves through buf[1]; frags -> registers ----
  float x2a = 0.0f;
  bf16x8 a[4][8];
  for (int h = 0; h < 2; ++h) {
#pragma unroll
    for (int st = 0; st < 8; ++st) {
      int f8 = st * 256 + tid;         // 8-float unit id within half
      int r  = f8 >> 5;                // local row 0..63
      int u  = f8 & 31;
      const float* src = x + (size_t)(row0 + h * 64 + r) * DIM + u * 8;
      f32x4 v0 = __builtin_nontemporal_load((const f32x4*)src);
      f32x4 v1 = __builtin_nontemporal_load(((const f32x4*)src) + 1);
      x2a += v0[0] * v0[0] + v0[1] * v0[1] + v0[2] * v0[2] + v0[3] * v0[3]
           + v1[0] * v1[0] + v1[1] * v1[1] + v1[2] * v1[2] + v1[3] * v1[3];
      union { bf16x8 v; short s[8]; } pk;
      pk.s[0] = f2bf(v0[0]); pk.s[1] = f2bf(v0[1]); pk.s[2] = f2bf(v0[2]); pk.s[3] = f2bf(v0[3]);
      pk.s[4] = f2bf(v1[0]); pk.s[5] = f2bf(v1[1]); pk.s[6] = f2bf(v1[2]); pk.s[7] = f2bf(v1[3]);
      *(bf16x8*)&buf[1][r * 256 + ((u ^ (r & 15)) << 3)] = pk.v;
    }
    __syncthreads();
    if (wr == h) {
#pragma unroll
      for (int mi = 0; mi < 4; ++mi)
#pragma unroll
        for (int kk = 0; kk < 8; ++kk) {
          int rl = mi * 16 + l15;      // local row; rl & 15 == l15
          a[mi][kk] = *(const bf16x8*)&buf[1][rl * 256 + (((kk * 4 + lhi) ^ l15) << 3)];
        }
    }
    __syncthreads();
  }

  float bk[4][4];
#pragma unroll
  for (int i = 0; i < 4; ++i)
#pragma unroll
    for (int r = 0; r < 4; ++r) bk[i][r] = -__builtin_inff();

  // ---- chunk loop: prefetch c+1, compute c, one barrier per chunk ----
  for (int c = 0; c < NCHUNK; ++c) {
    const int cur = c & 1;
    if (c + 1 < NCHUNK) {
      const short* gb = ebf + (c + 1) * (CHUNK * 256);
#pragma unroll
      for (int it = 0; it < 8; ++it)
        gload_lds16(gb + it * 2048 + tid * 8, &buf[cur ^ 1][it * 2048 + tid * 8]);
    }

    float ct[2]; unsigned tr[2];
#pragma unroll
    for (int n2 = 0; n2 < 2; ++n2) {
      int code = c * CHUNK + wc * 32 + n2 * 16 + l15;
      ct[n2] = cneg[code];
      tr[n2] = (unsigned)(1023 - code);
    }

    f32x4 acc[4][2];
#pragma unroll
    for (int mi = 0; mi < 4; ++mi)
#pragma unroll
      for (int n2 = 0; n2 < 2; ++n2) acc[mi][n2] = f32x4{0.f, 0.f, 0.f, 0.f};

#pragma unroll
    for (int kk = 0; kk < 8; ++kk) {
      bf16x8 b[2];
#pragma unroll
      for (int n2 = 0; n2 < 2; ++n2) {
        int cl = wc * 32 + n2 * 16 + l15;          // cl & 15 == l15 == code & 15
        b[n2] = *(const bf16x8*)&buf[cur][cl * 256 + (((kk * 4 + lhi) ^ l15) << 3)];
      }
#pragma unroll
      for (int mi = 0; mi < 4; ++mi)
#pragma unroll
        for (int n2 = 0; n2 < 2; ++n2)
          acc[mi][n2] = __builtin_amdgcn_mfma_f32_16x16x32_bf16(a[mi][kk], b[n2], acc[mi][n2], 0, 0, 0);
    }

    // fold into running best keys: key = (sv & ~1023) | (1023-code)
#pragma unroll
    for (int mi = 0; mi < 4; ++mi)
#pragma unroll
      for (int n2 = 0; n2 < 2; ++n2)
#pragma unroll
        for (int r = 0; r < 4; ++r) {
          float sv = acc[mi][n2][r] + ct[n2];
          unsigned kb = (__float_as_uint(sv) & 0xFFFFFC00u) | tr[n2];
          bk[mi][r] = fmaxf(bk[mi][r], __uint_as_float(kb));
        }

    __syncthreads();   // drains prefetch (c+1 ready) + frees buf[cur] readers
  }

  // ---- reduce across 16 code-lanes, resolve per-row winner ----
#pragma unroll
  for (int mi = 0; mi < 4; ++mi)
#pragma unroll
    for (int r = 0; r < 4; ++r) {
      float v = bk[mi][r];
#pragma unroll
      for (int off = 1; off < 16; off <<= 1) v = fmaxf(v, __shfl_xor(v, off, 64));
      if (l15 == 0) cands[wc][wr * 64 + mi * 16 + lhi * 4 + r] = v;
    }
  __syncthreads();

  float sv = 0.0f;
  if (tid < 128) {
    float k = fmaxf(cands[0][tid], cands[1][tid]);
    unsigned ku = __float_as_uint(k);
    codes[tid] = 1023 - (int)(ku & 1023u);
    sv = __uint_as_float(ku & 0xFFFFFC00u);
  }
  red[tid] = x2a - 2.0f * sv;          // block partial: sum x^2 - 2*sum sv
  __syncthreads();
  for (int s = 128; s > 0; s >>= 1) {
    if (tid < s) red[tid] += red[tid + s];
    __syncthreads();
  }
  if (tid == 0) partials[blockIdx.x] = red[0];

  // ---- fused gather: q = ew[code], exact fp32, nontemporal streamed write ----
#pragma unroll 8
  for (int j = 0; j < 32; ++j) {
    int f4 = j * 256 + tid;            // float4 id within the 128x256 tile
    int rw = f4 >> 6;
    int c4 = f4 & 63;
    int code = codes[rw];
    f32x4 qv = *((const f32x4*)(ew + (size_t)code * DIM) + c4);
    __builtin_nontemporal_store(qv, ((f32x4*)(qout + (size_t)(row0 + rw) * DIM)) + c4);
  }
}

// ---------------------------------------------------------------- final loss
__global__ __launch_bounds__(256) void loss_kernel(const float* __restrict__ partials,
                                                   float* __restrict__ out_loss) {
  __shared__ double red[256];
  double a = 0.0;
  for (int i = threadIdx.x; i < 512; i += 256) a += (double)partials[i];
  red[threadIdx.x] = a;
  __syncthreads();
  for (int s = 128; s > 0; s >>= 1) {
    if (threadIdx.x < s) red[threadIdx.x] += red[threadIdx.x + s];
    __syncthreads();
  }
  if (threadIdx.x == 0) out_loss[0] = (float)(1.25 * red[0] / 16777216.0);
}

// ---------------------------------------------------------------- launch
extern "C" void kernel_launch(void* const* d_in, const int* in_sizes, int n_in,
                              void* d_out, int out_size, void* d_ws, size_t ws_size,
                              hipStream_t stream) {
  const float* x  = (const float*)d_in[0];   // inputs [65536,256]
  const float* ew = (const float*)d_in[1];   // embed  [1024,256]
  float* out = (float*)d_out;

  char* ws = (char*)d_ws;
  short* ebf      = (short*)ws;                       // 512 KiB (pre-swizzled bf16)
  float* cneg     = (float*)(ws + 524288);            // 4 KiB
  float* partials = (float*)(ws + 528384);            // 2 KiB

  prep_kernel<<<NCODES, 64, 0, stream>>>(ew, ebf, cneg);
  vq_kernel<<<M_ROWS / 128, 256, 0, stream>>>(x, ebf, cneg, ew, out, partials);
  loss_kernel<<<1, 256, 0, stream>>>(partials, out + 16777216);
}